// Round 6
// baseline (225.638 us; speedup 1.0000x reference)
//
#include <hip/hip_runtime.h>
#include <math.h>

#define BB 8192
#define KK 32
#define DD 129      // hyperboloid dim = D + 1
#define VV 2048
#define NN 33       // K + 1
#define TOPK 10
#define WPB 4       // waves (= batches) per block; waves fully autonomous (no barriers)

__device__ __forceinline__ float fast_rcp(float x) { return __builtin_amdgcn_rcpf(x); }
__device__ __forceinline__ float dot4(float4 a, float4 b) {
    return fmaf(a.x, b.x, fmaf(a.y, b.y, fmaf(a.z, b.z, a.w * b.w)));
}

__global__ __launch_bounds__(256) void lr_fused(
    const float* __restrict__ anchor,
    const float* __restrict__ positive,
    const float* __restrict__ neg,
    const float* __restrict__ tree,
    const int* __restrict__ a_idx,
    const int* __restrict__ p_idx,
    const int* __restrict__ n_idx,
    float* __restrict__ partial)
{
    // per-wave private LDS slices: no __syncthreads anywhere
    __shared__ float  st_[WPB][NN];     // tree distances
    __shared__ float  sx_[WPB][NN];     // raw -inner (pre-acosh)
    __shared__ float  sd_[WPB][NN];     // d
    __shared__ float4 sitem[WPB][NN];   // {d, rel, disc, 0}

    const int t    = threadIdx.x;
    const int wave = t >> 6;
    const int lane = t & 63;
    const int g    = lane >> 4;        // 4 row-groups per wave
    const int subl = lane & 15;        // 16 lanes per row
    const int b    = blockIdx.x * WPB + wave;

    // ---- tree gather (lanes >=33 clamped dup, discarded) ----
    const int ai  = a_idx[b];
    const int col = (lane == 0) ? p_idx[b]
                                : n_idx[(size_t)b * KK + ((lane < NN ? lane : KK) - 1)];
    const float tg = tree[(size_t)ai * VV + col];
    if (lane < NN) st_[wave][lane] = tg;

    const float* ab = anchor   + (size_t)b * DD;
    const float* pb = positive + (size_t)b * DD;
    const float* nb = neg      + (size_t)b * (KK * DD);

    // ---- anchor: 2 float4 per lane (elems 4s..4s+3, 64+4s..64+4s+3) + e128 ----
    float4 aq0 = *(const float4*)(ab + 4 * subl);
    float4 aq1 = *(const float4*)(ab + 64 + 4 * subl);
    const float a128 = ab[128];

    // ---- burst-load all 33 rows as float4 pairs (9 rounds x 4 groups) ----
    const float* rp[9];
    #pragma unroll
    for (int r = 0; r < 9; ++r) {
        int row = 4 * r + g;
        if (row > KK) row = KK;
        rp[r] = (row == 0) ? pb : (nb + (size_t)(row - 1) * DD);
    }
    float4 v0[9], v1[9];
    float  t128[9];
    #pragma unroll
    for (int r = 0; r < 9; ++r) {
        v0[r]   = *(const float4*)(rp[r] + 4 * subl);
        v1[r]   = *(const float4*)(rp[r] + 64 + 4 * subl);
        t128[r] = rp[r][128];
    }

    // ---- dots: 8 FMAs/lane + 4-step shuffle; park raw -inner in LDS ----
    #pragma unroll
    for (int r = 0; r < 9; ++r) {
        float s = dot4(aq0, v0[r]) + dot4(aq1, v1[r]);
        s += __shfl_xor(s, 8, 64);
        s += __shfl_xor(s, 4, 64);
        s += __shfl_xor(s, 2, 64);
        s += __shfl_xor(s, 1, 64);
        int row = 4 * r + g;
        if (subl == 0 && row < NN) {
            float full = s + a128 * t128[r];          // sum_{0..128} a*v
            // -inner = 2*u0*v0 - full  (u0 = aq0.x, v0 = v0[r].x at subl==0)
            sx_[wave][row] = fmaxf(fmaf(2.0f * aq0.x, v0[r].x, -full), 1.0f + 1e-07f);
        }
    }

    // ---- dense acosh pass ----
    float dlane = 0.0f;
    if (lane < NN) {
        float x = sx_[wave][lane];
        dlane = __logf(x + sqrtf(x * x - 1.0f));      // acosh(x)
        sd_[wave][lane] = dlane;
    }

    // ---- rel + stable rank -> disc ----
    if (lane < NN) {
        float maxt = st_[wave][0];
        #pragma unroll
        for (int j = 1; j < NN; ++j) maxt = fmaxf(maxt, st_[wave][j]);
        float rel = (maxt - tg + 1e-06f) * fast_rcp(maxt + 1e-06f);

        int cnt = 0;
        #pragma unroll
        for (int j = 0; j < NN; ++j) {
            float dj = sd_[wave][j];
            cnt += (int)((dj < dlane) | ((dj == dlane) & (j < lane)));
        }
        float disc = (cnt + 1 <= TOPK) ? fast_rcp(log2f((float)(cnt + 2))) : 0.0f;
        sitem[wave][lane] = make_float4(dlane, rel, disc, 0.0f);
    }

    // ---- IDCG (stable descending position) -> inv broadcast in regs ----
    float c = 0.0f;
    if (lane < NN) {
        float ri = sitem[wave][lane].y;
        int pos = 0;
        #pragma unroll
        for (int j = 0; j < NN; ++j) {
            float rj = sitem[wave][j].y;
            pos += (int)((rj > ri) | ((rj == ri) & (j < lane)));
        }
        if (pos < TOPK) c = ri * fast_rcp(log2f((float)(pos + 2)));
    }
    #pragma unroll
    for (int off = 32; off > 0; off >>= 1) c += __shfl_xor(c, off, 64);
    const float inv = (c > 0.0f) ? fast_rcp(c) : 0.0f;

    // ---- pair sum over i<j (symmetric term: full sum = 2 * this) ----
    float acc = 0.0f;
    #pragma unroll
    for (int it = 0; it < 9; ++it) {
        int p = it * 64 + lane;                  // 0..575
        float vmask = (p < 528) ? 1.0f : 0.0f;
        int pc = (p < 528) ? p : 527;
        int j = (int)((1.0f + sqrtf((float)(8 * pc + 1))) * 0.5f);
        int tj = (j * (j - 1)) >> 1;
        if (tj > pc) { --j; tj = (j * (j - 1)) >> 1; }
        int i = pc - tj;
        float4 Ii = sitem[wave][i];
        float4 Ij = sitem[wave][j];
        float dd    = Ij.x - Ii.x;               // d[j] - d[i]
        float drel  = Ii.y - Ij.y;
        float ddisc = Ii.z - Ij.z;
        float t1  = drel * fabsf(ddisc) * (inv * vmask);   // S * delta (masked)
        float e   = __expf(-dd);
        float num = (drel >= 0.0f) ? 1.0f : e;
        acc = fmaf(t1 * num * fast_rcp(1.0f + e), -dd, acc);
    }
    #pragma unroll
    for (int off = 32; off > 0; off >>= 1) acc += __shfl_xor(acc, off, 64);
    if (lane == 0) partial[b] = acc;             // == 0.5 * full pair sum
}

__global__ __launch_bounds__(256) void lr_reduce(
    const float* __restrict__ partial, float* __restrict__ out)
{
    __shared__ float swave[4];
    const float4* p4 = (const float4*)partial;
    float acc = 0.0f;
    #pragma unroll
    for (int c = 0; c < (BB / 4) / 256; ++c) {
        float4 v = p4[c * 256 + threadIdx.x];
        acc += (v.x + v.y) + (v.z + v.w);
    }
    #pragma unroll
    for (int off = 32; off > 0; off >>= 1) acc += __shfl_xor(acc, off, 64);
    if ((threadIdx.x & 63) == 0) swave[threadIdx.x >> 6] = acc;
    __syncthreads();
    if (threadIdx.x == 0)
        out[0] = (swave[0] + swave[1] + swave[2] + swave[3]) * (0.15f / (float)BB);
}

extern "C" void kernel_launch(void* const* d_in, const int* in_sizes, int n_in,
                              void* d_out, int out_size, void* d_ws, size_t ws_size,
                              hipStream_t stream)
{
    const float* anchor   = (const float*)d_in[0];
    const float* positive = (const float*)d_in[1];
    const float* neg      = (const float*)d_in[2];
    const float* tree     = (const float*)d_in[3];
    const int*   a_idx    = (const int*)d_in[4];
    const int*   p_idx    = (const int*)d_in[5];
    const int*   n_idx    = (const int*)d_in[6];
    float* partial = (float*)d_ws;   // BB floats = 32 KB scratch

    lr_fused<<<BB / WPB, 256, 0, stream>>>(anchor, positive, neg, tree,
                                           a_idx, p_idx, n_idx, partial);
    lr_reduce<<<1, 256, 0, stream>>>(partial, (float*)d_out);
}